// Round 12
// baseline (632.783 us; speedup 1.0000x reference)
//
#include <hip/hip_runtime.h>
#include <hip/hip_bf16.h>

#define N_NODES 50000
#define N_EDGES 800000
#define LATENT 32
#define STEPS 10
#define NEG_SLOPE 0.01f
#define LN_EPS 1e-5f
#define SCAN_BLK 256
#define SCAN_NBLK ((N_NODES + SCAN_BLK - 1) / SCAN_BLK)  // 196
#define STG_STRIDE 36         // 16-row staging, +4 pad: 16B-aligned rows, 2-way banks
#define NODES_PER_BLOCK 32
#define STEP_BLOCKS ((N_NODES + NODES_PER_BLOCK - 1) / NODES_PER_BLOCK)  // 1563
#define CL_STRIDE 34          // cL[c][node] column layout, stride 34: 2-bank row skew

typedef __attribute__((ext_vector_type(8))) __bf16 bf16x8;
typedef __attribute__((ext_vector_type(4))) __bf16 bf16x4;
typedef __attribute__((ext_vector_type(4))) float f32x4;

__device__ __forceinline__ float leaky(float x) {
    return x >= 0.0f ? x : NEG_SLOPE * x;
}

__device__ __forceinline__ float4 f4fma(float a, float4 b, float4 c) {
    c.x += a * b.x; c.y += a * b.y; c.z += a * b.z; c.w += a * b.w;
    return c;
}

__device__ __forceinline__ bf16x4 pack4(float4 v) {
    bf16x4 o;
    o[0] = (__bf16)v.x; o[1] = (__bf16)v.y; o[2] = (__bf16)v.z; o[3] = (__bf16)v.w;
    return o;
}

// ---------------- node encoder ----------------

__global__ void encode_nodes_kernel(const float* __restrict__ x,
                                    const float* __restrict__ W,  // [6][32]
                                    const float* __restrict__ b,  // [32]
                                    float* __restrict__ h,
                                    __bf16* __restrict__ hbf) {
    __shared__ __align__(16) float Ws[6 * 32];
    __shared__ __align__(16) float bs[32];
    int tid = threadIdx.x;
    if (tid < 192) Ws[tid] = W[tid];
    if (tid < 32) bs[tid] = b[tid];
    __syncthreads();
    int n = blockIdx.x * blockDim.x + tid;
    if (n >= N_NODES) return;
    float xv[6];
#pragma unroll
    for (int k = 0; k < 6; k++) xv[k] = x[(size_t)n * 6 + k];
    float4 acc[8];
#pragma unroll
    for (int q = 0; q < 8; q++) acc[q] = *(const float4*)&bs[q * 4];
#pragma unroll
    for (int k = 0; k < 6; k++) {
#pragma unroll
        for (int q = 0; q < 8; q++) {
            float4 w = *(const float4*)&Ws[k * 32 + q * 4];
            acc[q] = f4fma(xv[k], w, acc[q]);
        }
    }
#pragma unroll
    for (int q = 0; q < 8; q++) {
        float4 o = acc[q];
        o.x = leaky(o.x); o.y = leaky(o.y); o.z = leaky(o.z); o.w = leaky(o.w);
        *(float4*)&h[(size_t)n * 32 + q * 4] = o;
        *(bf16x4*)&hbf[(size_t)n * 32 + q * 4] = pack4(o);
    }
}

// ---------------- CSR build (once per launch) ----------------
// TOMBSTONE (round 18): perm_build/gather split — scattered 4-B perm write
// alone cost 55 us (WRITE_SIZE 52 MB). ANY scattered-write pass costs
// ~50-65 us; fused scatter_encode is the minimum-pass structure.
// TOMBSTONE (rounds 24/25): pipeline-depth ladder mapped — d1:710, d2:636,
// d3:716, d4:947(spill at VGPR=64 class). DEPTH-2 IS OPTIMAL; do not
// revisit. launch_bounds' 2nd arg is a MINIMUM occupancy, not a cap.
// TOMBSTONE (round 27): persistent cooperative step loop FAILS CORRECTNESS
// on gfx950 — grid.sync() does not invalidate reader-side L1/L2 across
// XCDs; ping-pong h/hbf reads see stale lines (absmax 7.19). Kernel-launch
// boundary cache invalidation is load-bearing; per-step launches required.

__global__ void count_kernel(const int* __restrict__ recv, int* __restrict__ cnt) {
    int i = blockIdx.x * blockDim.x + threadIdx.x;
    if (i < N_EDGES) atomicAdd(&cnt[recv[i]], 1);
}

__global__ void csr_reduce_kernel(const int* __restrict__ cnt, int* __restrict__ partial) {
    __shared__ int sdata[SCAN_BLK];
    int tid = threadIdx.x;
    int idx = blockIdx.x * SCAN_BLK + tid;
    sdata[tid] = (idx < N_NODES) ? cnt[idx] : 0;
    __syncthreads();
#pragma unroll
    for (int off = SCAN_BLK / 2; off > 0; off >>= 1) {
        if (tid < off) sdata[tid] += sdata[tid + off];
        __syncthreads();
    }
    if (tid == 0) partial[blockIdx.x] = sdata[0];
}

__global__ void csr_scan_partials_kernel(int* __restrict__ partial,
                                         int* __restrict__ row_start) {
    __shared__ int sdata[SCAN_BLK];
    int tid = threadIdx.x;
    int v = (tid < SCAN_NBLK) ? partial[tid] : 0;
    sdata[tid] = v;
    __syncthreads();
#pragma unroll
    for (int off = 1; off < SCAN_BLK; off <<= 1) {
        int t = (tid >= off) ? sdata[tid - off] : 0;
        __syncthreads();
        sdata[tid] += t;
        __syncthreads();
    }
    if (tid < SCAN_NBLK) partial[tid] = sdata[tid] - v;  // exclusive
    if (tid == SCAN_BLK - 1) row_start[N_NODES] = sdata[SCAN_BLK - 1];
}

__global__ void csr_apply_kernel(const int* __restrict__ cnt,
                                 const int* __restrict__ partial,
                                 int* __restrict__ row_start,
                                 int* __restrict__ cursor) {
    __shared__ int sdata[SCAN_BLK];
    int tid = threadIdx.x;
    int idx = blockIdx.x * SCAN_BLK + tid;
    int v = (idx < N_NODES) ? cnt[idx] : 0;
    sdata[tid] = v;
    __syncthreads();
#pragma unroll
    for (int off = 1; off < SCAN_BLK; off <<= 1) {
        int t = (tid >= off) ? sdata[tid - off] : 0;
        __syncthreads();
        sdata[tid] += t;
        __syncthreads();
    }
    if (idx < N_NODES) {
        int out = partial[blockIdx.x] + sdata[tid] - v;
        row_start[idx] = out;
        cursor[idx] = out;
    }
}

// fused scatter + permute + edge-encode. Plain stores. (s,r) packed uint32.
// TOMBSTONE (round 14): nontemporal e-row stores = write-through/no-combine
// on gfx950 -> WRITE_SIZE 107->167 MB, dur 65->114 us.
__global__ void scatter_encode_kernel(const float* __restrict__ ea,
                                      const int* __restrict__ senders,
                                      const int* __restrict__ receivers,
                                      int* __restrict__ cursor,
                                      const float* __restrict__ W,  // [3][32]
                                      const float* __restrict__ b,  // [32]
                                      __bf16* __restrict__ e,
                                      unsigned int* __restrict__ sr_p) {
    __shared__ __align__(16) float Ws[3 * 32];
    __shared__ __align__(16) float bs[32];
    int tid = threadIdx.x;
    if (tid < 96) Ws[tid] = W[tid];
    if (tid < 32) bs[tid] = b[tid];
    __syncthreads();
    int i = blockIdx.x * blockDim.x + tid;
    if (i >= N_EDGES) return;
    int s = senders[i];
    int r = receivers[i];
    float xv[3];
#pragma unroll
    for (int k = 0; k < 3; k++) xv[k] = ea[(size_t)i * 3 + k];
    int pos = atomicAdd(&cursor[r], 1);
    float4 acc[8];
#pragma unroll
    for (int q = 0; q < 8; q++) acc[q] = *(const float4*)&bs[q * 4];
#pragma unroll
    for (int k = 0; k < 3; k++) {
#pragma unroll
        for (int q = 0; q < 8; q++) {
            float4 w = *(const float4*)&Ws[k * 32 + q * 4];
            acc[q] = f4fma(xv[k], w, acc[q]);
        }
    }
    __bf16* er = e + (size_t)pos * 32;
#pragma unroll
    for (int q = 0; q < 4; q++) {
        float4 lo = acc[2 * q], hi = acc[2 * q + 1];
        bf16x8 v;
        v[0] = (__bf16)leaky(lo.x); v[1] = (__bf16)leaky(lo.y);
        v[2] = (__bf16)leaky(lo.z); v[3] = (__bf16)leaky(lo.w);
        v[4] = (__bf16)leaky(hi.x); v[5] = (__bf16)leaky(hi.y);
        v[6] = (__bf16)leaky(hi.z); v[7] = (__bf16)leaky(hi.w);
        *(bf16x8*)(er + q * 8) = v;
    }
    sr_p[pos] = (unsigned int)s | ((unsigned int)r << 16);
}

// ---------------- fused per-step kernel: edge MFMA + node update ----------
// ROUND 28: exact round-26 kernel (632 us verified best). Phase 1: depth-2
// register pipeline (OPTIMAL — depth-ladder tombstone), LDS-transpose
// epilogue. Phase 2: own-output MLP via cL column staging. Decoder fused
// into the last step via runtime `last` flag.
// TOMBSTONE: ds_add_f32 agg on sorted receivers = same-address serial
// (r6: 47->178 us). TOMBSTONE: pipeline THROUGH LDS corrupts (r8-10).

__global__ __launch_bounds__(256, 3) void fused_step_kernel(
    __bf16* __restrict__ e,                // [E][32] in/out, receiver-sorted
    const __bf16* __restrict__ hbf_in,     // [N][32] h_s (bf16)
    __bf16* __restrict__ hbf_out,          // [N][32] h_{s+1} (bf16)
    const float* __restrict__ h_in,        // [N][32] h_s (f32)
    float* __restrict__ h_out,             // [N][32] h_{s+1} (f32)
    const unsigned int* __restrict__ srp,  // [E] s | (r<<16)
    const int* __restrict__ row_start,     // [N+1]
    const float* __restrict__ eW,          // [96][32]
    const float* __restrict__ eb,          // [32]
    const float* __restrict__ els,         // [32]
    const float* __restrict__ elb,         // [32]
    const float* __restrict__ nW,          // [64][32]
    const float* __restrict__ nb,          // [32]
    const float* __restrict__ nls,         // [32]
    const float* __restrict__ nlb,         // [32]
    const float* __restrict__ dW1,         // [32][32] decoder (last step only)
    const float* __restrict__ db1,         // [32]
    const float* __restrict__ dW2,         // [32]
    const float* __restrict__ db2,         // [1]
    float* __restrict__ out,               // [N]
    int last) {
    __shared__ __align__(16) float stg[4][16 * STG_STRIDE];   // 9216 B
    __shared__ __align__(16) float Ws[64 * 32];               // 8192 B (linear)
    __shared__ __align__(16) float cL[64 * CL_STRIDE];        // 8704 B
    __shared__ __align__(16) float prm[96];                   // 384 B

    int tid = threadIdx.x;
    const int wave = tid >> 6;
    const int lane = tid & 63;
    const int n_ = lane & 15;
    const int quad = lane >> 4;
    const int rr = lane >> 2;   // epilogue row 0..15
    const int jj = lane & 3;    // epilogue col-quarter

    // stage node-side weights (linear) / params; consumed after phase barrier
    {
        const float4* Wg = (const float4*)nW;
        float4* Wl = (float4*)Ws;
        Wl[tid] = Wg[tid];
        Wl[tid + 256] = Wg[tid + 256];
        if (tid < 32) {
            prm[tid] = nb[tid];
            prm[32 + tid] = nls[tid];
            prm[64 + tid] = nlb[tid];
        }
    }

    // edge-side B fragments straight from global (L2-hot 12 KB)
    bf16x8 bfr[3][2];
#pragma unroll
    for (int kc = 0; kc < 3; kc++)
#pragma unroll
        for (int oh = 0; oh < 2; oh++) {
            bf16x8 f;
#pragma unroll
            for (int j = 0; j < 8; j++)
                f[j] = (__bf16)eW[(kc * 32 + quad * 8 + j) * 32 + oh * 16 + n_];
            bfr[kc][oh] = f;
        }
    float bia0 = eb[n_], bia1 = eb[16 + n_];
    float lns8[8], lnb8[8];
    {
        f32x4 sa = *(const f32x4*)&els[jj * 8];
        f32x4 sb = *(const f32x4*)&els[jj * 8 + 4];
        f32x4 ba = *(const f32x4*)&elb[jj * 8];
        f32x4 bb = *(const f32x4*)&elb[jj * 8 + 4];
#pragma unroll
        for (int i = 0; i < 4; i++) {
            lns8[i] = sa[i]; lns8[4 + i] = sb[i];
            lnb8[i] = ba[i]; lnb8[4 + i] = bb[i];
        }
    }

    const int n0 = blockIdx.x * NODES_PER_BLOCK;
    const int nn = min(NODES_PER_BLOCK, N_NODES - n0);
    const int beg = row_start[n0];
    const int end = row_start[n0 + nn];
    const int nt = (end - beg + 15) >> 4;   // padded 16-edge tiles
    float* mystg = stg[wave];

    // ---------------- phase 1: edge update (depth-2 register pipeline) ----
    unsigned int srA = 0;   // srp for the tile two pipeline-slots ahead
    bf16x8 aE0{}, aS0{}, aR0{}, old0{};
    bf16x8 aE1{}, aS1{}, aR1{}, old1{};
    if (wave < nt) {
        int jb = beg + wave * 16;
        int ja = min(jb + n_, N_EDGES - 1);
        unsigned int sr = srp[ja];
        aE0  = *(const bf16x8*)&e[(size_t)ja * 32 + quad * 8];
        aS0  = *(const bf16x8*)&hbf_in[(size_t)(sr & 0xFFFFu) * 32 + quad * 8];
        aR0  = *(const bf16x8*)&hbf_in[(size_t)(sr >> 16) * 32 + quad * 8];
        old0 = *(const bf16x8*)&e[(size_t)min(jb + rr, N_EDGES - 1) * 32 + jj * 8];
    }
    if (wave + 4 < nt) {
        int jb = beg + (wave + 4) * 16;
        int ja = min(jb + n_, N_EDGES - 1);
        unsigned int sr = srp[ja];
        aE1  = *(const bf16x8*)&e[(size_t)ja * 32 + quad * 8];
        aS1  = *(const bf16x8*)&hbf_in[(size_t)(sr & 0xFFFFu) * 32 + quad * 8];
        aR1  = *(const bf16x8*)&hbf_in[(size_t)(sr >> 16) * 32 + quad * 8];
        old1 = *(const bf16x8*)&e[(size_t)min(jb + rr, N_EDGES - 1) * 32 + jj * 8];
    }
    if (wave + 8 < nt)
        srA = srp[min(beg + (wave + 8) * 16 + n_, N_EDGES - 1)];

    for (int t = wave; t < nt; t += 4) {
        int e0 = beg + t * 16;

        f32x4 acc[2] = {{0.f, 0.f, 0.f, 0.f}, {0.f, 0.f, 0.f, 0.f}};
#pragma unroll
        for (int oh = 0; oh < 2; oh++) {
            acc[oh] = __builtin_amdgcn_mfma_f32_16x16x32_bf16(aE0, bfr[0][oh], acc[oh], 0, 0, 0);
            acc[oh] = __builtin_amdgcn_mfma_f32_16x16x32_bf16(aS0, bfr[1][oh], acc[oh], 0, 0, 0);
            acc[oh] = __builtin_amdgcn_mfma_f32_16x16x32_bf16(aR0, bfr[2][oh], acc[oh], 0, 0, 0);
        }

        // issue loads for tile t+8 (two slots ahead; covered by ~2 tiles of work)
        bf16x8 aE2 = aE0, aS2 = aS0, aR2 = aR0, old2 = old0;
        if (t + 8 < nt) {
            int jb = beg + (t + 8) * 16;
            int ja = min(jb + n_, N_EDGES - 1);
            aE2  = *(const bf16x8*)&e[(size_t)ja * 32 + quad * 8];
            aS2  = *(const bf16x8*)&hbf_in[(size_t)(srA & 0xFFFFu) * 32 + quad * 8];
            aR2  = *(const bf16x8*)&hbf_in[(size_t)(srA >> 16) * 32 + quad * 8];
            old2 = *(const bf16x8*)&e[(size_t)min(jb + rr, N_EDGES - 1) * 32 + jj * 8];
        }
        if (t + 12 < nt)
            srA = srp[min(beg + (t + 12) * 16 + n_, N_EDGES - 1)];

        // stage leaky(acc+bias) to LDS transpose buffer
#pragma unroll
        for (int oh = 0; oh < 2; oh++)
#pragma unroll
            for (int g = 0; g < 4; g++)
                mystg[(quad * 4 + g) * STG_STRIDE + oh * 16 + n_] =
                    leaky(acc[oh][g] + (oh ? bia1 : bia0));
        __builtin_amdgcn_wave_barrier();

        // re-role: lane handles row rr, cols jj*8 .. jj*8+8
        f32x4 va = *(const f32x4*)&mystg[rr * STG_STRIDE + jj * 8];
        f32x4 vb = *(const f32x4*)&mystg[rr * STG_STRIDE + jj * 8 + 4];
        float s1 = va[0] + va[1] + va[2] + va[3] + vb[0] + vb[1] + vb[2] + vb[3];
        float s2 = va[0]*va[0] + va[1]*va[1] + va[2]*va[2] + va[3]*va[3]
                 + vb[0]*vb[0] + vb[1]*vb[1] + vb[2]*vb[2] + vb[3]*vb[3];
        s1 += __shfl_xor(s1, 1);  s2 += __shfl_xor(s2, 1);
        s1 += __shfl_xor(s1, 2);  s2 += __shfl_xor(s2, 2);
        float mu = s1 * (1.0f / 32.0f);
        float var = s2 * (1.0f / 32.0f) - mu * mu;
        float inv = rsqrtf(fmaxf(var, 0.0f) + LN_EPS);

        float v[8] = {va[0], va[1], va[2], va[3], vb[0], vb[1], vb[2], vb[3]};
        bf16x8 outp;
#pragma unroll
        for (int i = 0; i < 8; i++)
            outp[i] = (__bf16)((float)old0[i] + (v[i] - mu) * inv * lns8[i] + lnb8[i]);
        if (e0 + rr < end)
            *(bf16x8*)&e[(size_t)(e0 + rr) * 32 + jj * 8] = outp;  // coalesced 16B
        __builtin_amdgcn_wave_barrier();

        aE0 = aE1; aS0 = aS1; aR0 = aR1; old0 = old1;
        aE1 = aE2; aS1 = aS2; aR1 = aR2; old1 = old2;
    }

    __syncthreads();   // phase boundary: all e-rows of this block written

    // ---------------- phase 2: node update (8 threads / node, own-output) -
    const int nl = tid >> 3;   // node-local 0..31
    const int oc = tid & 7;    // output col quad: cols oc*4 .. oc*4+4
    const bool act = nl < nn;
    const int n = n0 + nl;
    float hv4[4] = {0.f, 0.f, 0.f, 0.f};
    float res[4] = {0.f, 0.f, 0.f, 0.f};
    if (act) {
        int bn = row_start[n], en = row_start[n + 1];
        float s4[4] = {0.f, 0.f, 0.f, 0.f};
        int j = bn;
        for (; j + 7 < en; j += 8) {
            bf16x4 v0 = *(const bf16x4*)&e[(size_t)(j + 0) * 32 + oc * 4];
            bf16x4 v1 = *(const bf16x4*)&e[(size_t)(j + 1) * 32 + oc * 4];
            bf16x4 v2 = *(const bf16x4*)&e[(size_t)(j + 2) * 32 + oc * 4];
            bf16x4 v3 = *(const bf16x4*)&e[(size_t)(j + 3) * 32 + oc * 4];
            bf16x4 v4 = *(const bf16x4*)&e[(size_t)(j + 4) * 32 + oc * 4];
            bf16x4 v5 = *(const bf16x4*)&e[(size_t)(j + 5) * 32 + oc * 4];
            bf16x4 v6 = *(const bf16x4*)&e[(size_t)(j + 6) * 32 + oc * 4];
            bf16x4 v7 = *(const bf16x4*)&e[(size_t)(j + 7) * 32 + oc * 4];
#pragma unroll
            for (int k = 0; k < 4; k++)
                s4[k] += ((float)v0[k] + (float)v1[k]) + ((float)v2[k] + (float)v3[k])
                       + ((float)v4[k] + (float)v5[k]) + ((float)v6[k] + (float)v7[k]);
        }
        for (; j < en; j++) {
            bf16x4 v = *(const bf16x4*)&e[(size_t)j * 32 + oc * 4];
#pragma unroll
            for (int k = 0; k < 4; k++) s4[k] += (float)v[k];
        }
        float ic = 1.0f / fmaxf((float)(en - bn), 1.0f);
        float4 hvv = *(const float4*)&h_in[(size_t)n * 32 + oc * 4];
        hv4[0] = hvv.x; hv4[1] = hvv.y; hv4[2] = hvv.z; hv4[3] = hvv.w;
        // stage this thread's 8 c-values into the column-layout cL
#pragma unroll
        for (int i = 0; i < 4; i++) {
            cL[(oc * 4 + i) * CL_STRIDE + nl] = hv4[i];
            cL[(32 + oc * 4 + i) * CL_STRIDE + nl] = s4[i] * ic;
        }
    }
    __syncthreads();
    if (act) {
        float4 acc = *(const float4*)&prm[oc * 4];
#pragma unroll
        for (int k = 0; k < 64; k++) {
            float ck = cL[k * CL_STRIDE + nl];                 // oc-broadcast
            acc = f4fma(ck, *(const float4*)&Ws[k * 32 + oc * 4], acc);
        }
        float m4[4] = {leaky(acc.x), leaky(acc.y), leaky(acc.z), leaky(acc.w)};
        float s1 = m4[0] + m4[1] + m4[2] + m4[3];
        float s2 = m4[0]*m4[0] + m4[1]*m4[1] + m4[2]*m4[2] + m4[3]*m4[3];
        s1 += __shfl_xor(s1, 1);  s2 += __shfl_xor(s2, 1);
        s1 += __shfl_xor(s1, 2);  s2 += __shfl_xor(s2, 2);
        s1 += __shfl_xor(s1, 4);  s2 += __shfl_xor(s2, 4);
        float mu = s1 * (1.0f / 32.0f);
        float var = s2 * (1.0f / 32.0f) - mu * mu;
        float inv = rsqrtf(fmaxf(var, 0.0f) + LN_EPS);
#pragma unroll
        for (int k = 0; k < 4; k++)
            res[k] = hv4[k] + (m4[k] - mu) * inv * prm[32 + oc * 4 + k] + prm[64 + oc * 4 + k];
        float4 r0 = {res[0], res[1], res[2], res[3]};
        *(float4*)&h_out[(size_t)n * 32 + oc * 4] = r0;
        *(bf16x4*)&hbf_out[(size_t)n * 32 + oc * 4] = pack4(r0);
    }

    // ---------------- fused decoder (last step only) ----------------------
    if (last) {
        __syncthreads();   // all cL reads of the MLP above are complete
        if (act) {
#pragma unroll
            for (int i = 0; i < 4; i++)
                cL[(oc * 4 + i) * CL_STRIDE + nl] = res[i];   // stage final h row
        }
        __syncthreads();
        if (act) {
            float4 z = *(const float4*)&db1[oc * 4];
#pragma unroll
            for (int k = 0; k < 32; k++) {
                float ck = cL[k * CL_STRIDE + nl];             // oc-broadcast
                z = f4fma(ck, *(const float4*)&dW1[k * 32 + oc * 4], z);
            }
            float4 w2 = *(const float4*)&dW2[oc * 4];
            float o = leaky(z.x) * w2.x + leaky(z.y) * w2.y
                    + leaky(z.z) * w2.z + leaky(z.w) * w2.w;
            o += __shfl_xor(o, 1);
            o += __shfl_xor(o, 2);
            o += __shfl_xor(o, 4);
            if (oc == 0) out[n] = o + db2[0];
        }
    }
}

// ---------------- launch ----------------

extern "C" void kernel_launch(void* const* d_in, const int* in_sizes, int n_in,
                              void* d_out, int out_size, void* d_ws, size_t ws_size,
                              hipStream_t stream) {
    const float* x          = (const float*)d_in[0];
    const float* edge_attr  = (const float*)d_in[1];
    const int*   senders    = (const int*)d_in[2];
    const int*   receivers  = (const int*)d_in[3];
    const float* node_enc_W = (const float*)d_in[4];
    const float* node_enc_b = (const float*)d_in[5];
    const float* edge_enc_W = (const float*)d_in[6];
    const float* edge_enc_b = (const float*)d_in[7];
    const float* edge_W     = (const float*)d_in[8];
    const float* edge_b     = (const float*)d_in[9];
    const float* edge_ln_s  = (const float*)d_in[10];
    const float* edge_ln_b  = (const float*)d_in[11];
    const float* node_W     = (const float*)d_in[12];
    const float* node_b     = (const float*)d_in[13];
    const float* node_ln_s  = (const float*)d_in[14];
    const float* node_ln_b  = (const float*)d_in[15];
    const float* dec_W1     = (const float*)d_in[16];
    const float* dec_b1     = (const float*)d_in[17];
    const float* dec_W2     = (const float*)d_in[18];
    const float* dec_b2     = (const float*)d_in[19];
    float* out = (float*)d_out;

    char* ws = (char*)d_ws;
    size_t off = 0;
    auto alloc = [&](size_t bytes) -> void* {
        void* p = ws + off;
        off = (off + bytes + 255) & ~(size_t)255;
        return p;
    };
    float*        h0        = (float*)alloc((size_t)N_NODES * 32 * 4);
    float*        h1        = (float*)alloc((size_t)N_NODES * 32 * 4);
    __bf16*       hbf0      = (__bf16*)alloc((size_t)N_NODES * 32 * 2);
    __bf16*       hbf1      = (__bf16*)alloc((size_t)N_NODES * 32 * 2);
    __bf16*       e         = (__bf16*)alloc((size_t)N_EDGES * 32 * 2);
    int*          cnt       = (int*)alloc((size_t)N_NODES * 4);
    int*          row_start = (int*)alloc((size_t)(N_NODES + 1) * 4);
    int*          cursor    = (int*)alloc((size_t)N_NODES * 4);
    unsigned int* sr_p      = (unsigned int*)alloc((size_t)N_EDGES * 4);
    int*          partial   = (int*)alloc((size_t)SCAN_BLK * 4);
    (void)ws_size; (void)in_sizes; (void)n_in; (void)out_size;

    hipMemsetAsync(cnt, 0, (size_t)N_NODES * 4, stream);
    encode_nodes_kernel<<<(N_NODES + 255) / 256, 256, 0, stream>>>(x, node_enc_W, node_enc_b, h0, hbf0);
    count_kernel<<<(N_EDGES + 255) / 256, 256, 0, stream>>>(receivers, cnt);
    csr_reduce_kernel<<<SCAN_NBLK, SCAN_BLK, 0, stream>>>(cnt, partial);
    csr_scan_partials_kernel<<<1, SCAN_BLK, 0, stream>>>(partial, row_start);
    csr_apply_kernel<<<SCAN_NBLK, SCAN_BLK, 0, stream>>>(cnt, partial, row_start, cursor);
    scatter_encode_kernel<<<(N_EDGES + 255) / 256, 256, 0, stream>>>(
        edge_attr, senders, receivers, cursor, edge_enc_W, edge_enc_b, e, sr_p);

    float*  hbufs[2]  = {h0, h1};
    __bf16* hbbufs[2] = {hbf0, hbf1};
    for (int s = 0; s < STEPS; s++) {
        int in = s & 1, outb = 1 - in;
        fused_step_kernel<<<STEP_BLOCKS, 256, 0, stream>>>(
            e, hbbufs[in], hbbufs[outb], hbufs[in], hbufs[outb],
            sr_p, row_start,
            edge_W + (size_t)s * 96 * 32, edge_b + s * 32,
            edge_ln_s + s * 32, edge_ln_b + s * 32,
            node_W + (size_t)s * 64 * 32, node_b + s * 32,
            node_ln_s + s * 32, node_ln_b + s * 32,
            dec_W1, dec_b1, dec_W2, dec_b2, out,
            (s == STEPS - 1) ? 1 : 0);
    }
}

// Round 14
// 630.791 us; speedup vs baseline: 1.0032x; 1.0032x over previous
//
#include <hip/hip_runtime.h>
#include <hip/hip_bf16.h>

#define N_NODES 50000
#define N_EDGES 800000
#define LATENT 32
#define STEPS 10
#define NEG_SLOPE 0.01f
#define LN_EPS 1e-5f
#define SCAN_BLK 256
#define SCAN_NBLK ((N_NODES + SCAN_BLK - 1) / SCAN_BLK)  // 196
#define STG_STRIDE 36         // 16-row staging, +4 pad: 16B-aligned rows, 2-way banks
#define NODES_PER_BLOCK 32
#define STEP_BLOCKS ((N_NODES + NODES_PER_BLOCK - 1) / NODES_PER_BLOCK)  // 1563
#define CL_STRIDE 34          // cL[c][node] column layout, stride 34: 2-bank row skew

typedef __attribute__((ext_vector_type(8))) __bf16 bf16x8;
typedef __attribute__((ext_vector_type(4))) __bf16 bf16x4;
typedef __attribute__((ext_vector_type(4))) float f32x4;

__device__ __forceinline__ float leaky(float x) {
    return x >= 0.0f ? x : NEG_SLOPE * x;
}

__device__ __forceinline__ float4 f4fma(float a, float4 b, float4 c) {
    c.x += a * b.x; c.y += a * b.y; c.z += a * b.z; c.w += a * b.w;
    return c;
}

__device__ __forceinline__ bf16x4 pack4(float4 v) {
    bf16x4 o;
    o[0] = (__bf16)v.x; o[1] = (__bf16)v.y; o[2] = (__bf16)v.z; o[3] = (__bf16)v.w;
    return o;
}

// ---------------- node encoder ----------------

__global__ void encode_nodes_kernel(const float* __restrict__ x,
                                    const float* __restrict__ W,  // [6][32]
                                    const float* __restrict__ b,  // [32]
                                    float* __restrict__ h,
                                    __bf16* __restrict__ hbf) {
    __shared__ __align__(16) float Ws[6 * 32];
    __shared__ __align__(16) float bs[32];
    int tid = threadIdx.x;
    if (tid < 192) Ws[tid] = W[tid];
    if (tid < 32) bs[tid] = b[tid];
    __syncthreads();
    int n = blockIdx.x * blockDim.x + tid;
    if (n >= N_NODES) return;
    float xv[6];
#pragma unroll
    for (int k = 0; k < 6; k++) xv[k] = x[(size_t)n * 6 + k];
    float4 acc[8];
#pragma unroll
    for (int q = 0; q < 8; q++) acc[q] = *(const float4*)&bs[q * 4];
#pragma unroll
    for (int k = 0; k < 6; k++) {
#pragma unroll
        for (int q = 0; q < 8; q++) {
            float4 w = *(const float4*)&Ws[k * 32 + q * 4];
            acc[q] = f4fma(xv[k], w, acc[q]);
        }
    }
#pragma unroll
    for (int q = 0; q < 8; q++) {
        float4 o = acc[q];
        o.x = leaky(o.x); o.y = leaky(o.y); o.z = leaky(o.z); o.w = leaky(o.w);
        *(float4*)&h[(size_t)n * 32 + q * 4] = o;
        *(bf16x4*)&hbf[(size_t)n * 32 + q * 4] = pack4(o);
    }
}

// ---------------- CSR build (once per launch) ----------------
// TOMBSTONE (round 18): perm_build/gather split — scattered 4-B perm write
// alone cost 55 us (WRITE_SIZE 52 MB). ANY scattered-write pass costs
// ~50-65 us; fused scatter_encode is the minimum-pass structure.
// TOMBSTONE (rounds 24/25): pipeline-depth ladder mapped — d1:710, d2:636,
// d3:716, d4:947(spill at VGPR=64 class). DEPTH-2 IS OPTIMAL; do not
// revisit. launch_bounds' 2nd arg is a MINIMUM occupancy, not a cap.
// TOMBSTONE (rounds 27+29): persistent multi-step loops FAIL CORRECTNESS on
// gfx950 regardless of buffering (ping-pong AND fresh-buffer-per-step both
// absmax 7.19): threadfence+grid.sync does NOT write back the producer
// XCD's L2 to a point visible to other XCDs' fetches. Kernel-launch
// boundaries are the only safe cross-step visibility mechanism here.

__global__ void count_kernel(const int* __restrict__ recv, int* __restrict__ cnt) {
    int i = blockIdx.x * blockDim.x + threadIdx.x;
    if (i < N_EDGES) atomicAdd(&cnt[recv[i]], 1);
}

__global__ void csr_reduce_kernel(const int* __restrict__ cnt, int* __restrict__ partial) {
    __shared__ int sdata[SCAN_BLK];
    int tid = threadIdx.x;
    int idx = blockIdx.x * SCAN_BLK + tid;
    sdata[tid] = (idx < N_NODES) ? cnt[idx] : 0;
    __syncthreads();
#pragma unroll
    for (int off = SCAN_BLK / 2; off > 0; off >>= 1) {
        if (tid < off) sdata[tid] += sdata[tid + off];
        __syncthreads();
    }
    if (tid == 0) partial[blockIdx.x] = sdata[0];
}

__global__ void csr_scan_partials_kernel(int* __restrict__ partial,
                                         int* __restrict__ row_start) {
    __shared__ int sdata[SCAN_BLK];
    int tid = threadIdx.x;
    int v = (tid < SCAN_NBLK) ? partial[tid] : 0;
    sdata[tid] = v;
    __syncthreads();
#pragma unroll
    for (int off = 1; off < SCAN_BLK; off <<= 1) {
        int t = (tid >= off) ? sdata[tid - off] : 0;
        __syncthreads();
        sdata[tid] += t;
        __syncthreads();
    }
    if (tid < SCAN_NBLK) partial[tid] = sdata[tid] - v;  // exclusive
    if (tid == SCAN_BLK - 1) row_start[N_NODES] = sdata[SCAN_BLK - 1];
}

__global__ void csr_apply_kernel(const int* __restrict__ cnt,
                                 const int* __restrict__ partial,
                                 int* __restrict__ row_start,
                                 int* __restrict__ cursor) {
    __shared__ int sdata[SCAN_BLK];
    int tid = threadIdx.x;
    int idx = blockIdx.x * SCAN_BLK + tid;
    int v = (idx < N_NODES) ? cnt[idx] : 0;
    sdata[tid] = v;
    __syncthreads();
#pragma unroll
    for (int off = 1; off < SCAN_BLK; off <<= 1) {
        int t = (tid >= off) ? sdata[tid - off] : 0;
        __syncthreads();
        sdata[tid] += t;
        __syncthreads();
    }
    if (idx < N_NODES) {
        int out = partial[blockIdx.x] + sdata[tid] - v;
        row_start[idx] = out;
        cursor[idx] = out;
    }
}

// fused scatter + permute + edge-encode. Plain stores. (s,r) packed uint32.
// TOMBSTONE (round 14): nontemporal e-row stores = write-through/no-combine
// on gfx950 -> WRITE_SIZE 107->167 MB, dur 65->114 us.
__global__ void scatter_encode_kernel(const float* __restrict__ ea,
                                      const int* __restrict__ senders,
                                      const int* __restrict__ receivers,
                                      int* __restrict__ cursor,
                                      const float* __restrict__ W,  // [3][32]
                                      const float* __restrict__ b,  // [32]
                                      __bf16* __restrict__ e,
                                      unsigned int* __restrict__ sr_p) {
    __shared__ __align__(16) float Ws[3 * 32];
    __shared__ __align__(16) float bs[32];
    int tid = threadIdx.x;
    if (tid < 96) Ws[tid] = W[tid];
    if (tid < 32) bs[tid] = b[tid];
    __syncthreads();
    int i = blockIdx.x * blockDim.x + tid;
    if (i >= N_EDGES) return;
    int s = senders[i];
    int r = receivers[i];
    float xv[3];
#pragma unroll
    for (int k = 0; k < 3; k++) xv[k] = ea[(size_t)i * 3 + k];
    int pos = atomicAdd(&cursor[r], 1);
    float4 acc[8];
#pragma unroll
    for (int q = 0; q < 8; q++) acc[q] = *(const float4*)&bs[q * 4];
#pragma unroll
    for (int k = 0; k < 3; k++) {
#pragma unroll
        for (int q = 0; q < 8; q++) {
            float4 w = *(const float4*)&Ws[k * 32 + q * 4];
            acc[q] = f4fma(xv[k], w, acc[q]);
        }
    }
    __bf16* er = e + (size_t)pos * 32;
#pragma unroll
    for (int q = 0; q < 4; q++) {
        float4 lo = acc[2 * q], hi = acc[2 * q + 1];
        bf16x8 v;
        v[0] = (__bf16)leaky(lo.x); v[1] = (__bf16)leaky(lo.y);
        v[2] = (__bf16)leaky(lo.z); v[3] = (__bf16)leaky(lo.w);
        v[4] = (__bf16)leaky(hi.x); v[5] = (__bf16)leaky(hi.y);
        v[6] = (__bf16)leaky(hi.z); v[7] = (__bf16)leaky(hi.w);
        *(bf16x8*)(er + q * 8) = v;
    }
    sr_p[pos] = (unsigned int)s | ((unsigned int)r << 16);
}

// ---------------- fused per-step kernel: edge MFMA + node update ----------
// ROUND 30: exact round-26/28 kernel (632 us verified best; reproduced
// twice). Phase 1: depth-2 register pipeline (OPTIMAL — depth-ladder
// tombstone), LDS-transpose epilogue. Phase 2: own-output MLP via cL
// column staging. Decoder fused into the last step via runtime `last`.
// TOMBSTONE: ds_add_f32 agg on sorted receivers = same-address serial
// (r6: 47->178 us). TOMBSTONE: pipeline THROUGH LDS corrupts (r8-10).

__global__ __launch_bounds__(256, 3) void fused_step_kernel(
    __bf16* __restrict__ e,                // [E][32] in/out, receiver-sorted
    const __bf16* __restrict__ hbf_in,     // [N][32] h_s (bf16)
    __bf16* __restrict__ hbf_out,          // [N][32] h_{s+1} (bf16)
    const float* __restrict__ h_in,        // [N][32] h_s (f32)
    float* __restrict__ h_out,             // [N][32] h_{s+1} (f32)
    const unsigned int* __restrict__ srp,  // [E] s | (r<<16)
    const int* __restrict__ row_start,     // [N+1]
    const float* __restrict__ eW,          // [96][32]
    const float* __restrict__ eb,          // [32]
    const float* __restrict__ els,         // [32]
    const float* __restrict__ elb,         // [32]
    const float* __restrict__ nW,          // [64][32]
    const float* __restrict__ nb,          // [32]
    const float* __restrict__ nls,         // [32]
    const float* __restrict__ nlb,         // [32]
    const float* __restrict__ dW1,         // [32][32] decoder (last step only)
    const float* __restrict__ db1,         // [32]
    const float* __restrict__ dW2,         // [32]
    const float* __restrict__ db2,         // [1]
    float* __restrict__ out,               // [N]
    int last) {
    __shared__ __align__(16) float stg[4][16 * STG_STRIDE];   // 9216 B
    __shared__ __align__(16) float Ws[64 * 32];               // 8192 B (linear)
    __shared__ __align__(16) float cL[64 * CL_STRIDE];        // 8704 B
    __shared__ __align__(16) float prm[96];                   // 384 B

    int tid = threadIdx.x;
    const int wave = tid >> 6;
    const int lane = tid & 63;
    const int n_ = lane & 15;
    const int quad = lane >> 4;
    const int rr = lane >> 2;   // epilogue row 0..15
    const int jj = lane & 3;    // epilogue col-quarter

    // stage node-side weights (linear) / params; consumed after phase barrier
    {
        const float4* Wg = (const float4*)nW;
        float4* Wl = (float4*)Ws;
        Wl[tid] = Wg[tid];
        Wl[tid + 256] = Wg[tid + 256];
        if (tid < 32) {
            prm[tid] = nb[tid];
            prm[32 + tid] = nls[tid];
            prm[64 + tid] = nlb[tid];
        }
    }

    // edge-side B fragments straight from global (L2-hot 12 KB)
    bf16x8 bfr[3][2];
#pragma unroll
    for (int kc = 0; kc < 3; kc++)
#pragma unroll
        for (int oh = 0; oh < 2; oh++) {
            bf16x8 f;
#pragma unroll
            for (int j = 0; j < 8; j++)
                f[j] = (__bf16)eW[(kc * 32 + quad * 8 + j) * 32 + oh * 16 + n_];
            bfr[kc][oh] = f;
        }
    float bia0 = eb[n_], bia1 = eb[16 + n_];
    float lns8[8], lnb8[8];
    {
        f32x4 sa = *(const f32x4*)&els[jj * 8];
        f32x4 sb = *(const f32x4*)&els[jj * 8 + 4];
        f32x4 ba = *(const f32x4*)&elb[jj * 8];
        f32x4 bb = *(const f32x4*)&elb[jj * 8 + 4];
#pragma unroll
        for (int i = 0; i < 4; i++) {
            lns8[i] = sa[i]; lns8[4 + i] = sb[i];
            lnb8[i] = ba[i]; lnb8[4 + i] = bb[i];
        }
    }

    const int n0 = blockIdx.x * NODES_PER_BLOCK;
    const int nn = min(NODES_PER_BLOCK, N_NODES - n0);
    const int beg = row_start[n0];
    const int end = row_start[n0 + nn];
    const int nt = (end - beg + 15) >> 4;   // padded 16-edge tiles
    float* mystg = stg[wave];

    // ---------------- phase 1: edge update (depth-2 register pipeline) ----
    unsigned int srA = 0;   // srp for the tile two pipeline-slots ahead
    bf16x8 aE0{}, aS0{}, aR0{}, old0{};
    bf16x8 aE1{}, aS1{}, aR1{}, old1{};
    if (wave < nt) {
        int jb = beg + wave * 16;
        int ja = min(jb + n_, N_EDGES - 1);
        unsigned int sr = srp[ja];
        aE0  = *(const bf16x8*)&e[(size_t)ja * 32 + quad * 8];
        aS0  = *(const bf16x8*)&hbf_in[(size_t)(sr & 0xFFFFu) * 32 + quad * 8];
        aR0  = *(const bf16x8*)&hbf_in[(size_t)(sr >> 16) * 32 + quad * 8];
        old0 = *(const bf16x8*)&e[(size_t)min(jb + rr, N_EDGES - 1) * 32 + jj * 8];
    }
    if (wave + 4 < nt) {
        int jb = beg + (wave + 4) * 16;
        int ja = min(jb + n_, N_EDGES - 1);
        unsigned int sr = srp[ja];
        aE1  = *(const bf16x8*)&e[(size_t)ja * 32 + quad * 8];
        aS1  = *(const bf16x8*)&hbf_in[(size_t)(sr & 0xFFFFu) * 32 + quad * 8];
        aR1  = *(const bf16x8*)&hbf_in[(size_t)(sr >> 16) * 32 + quad * 8];
        old1 = *(const bf16x8*)&e[(size_t)min(jb + rr, N_EDGES - 1) * 32 + jj * 8];
    }
    if (wave + 8 < nt)
        srA = srp[min(beg + (wave + 8) * 16 + n_, N_EDGES - 1)];

    for (int t = wave; t < nt; t += 4) {
        int e0 = beg + t * 16;

        f32x4 acc[2] = {{0.f, 0.f, 0.f, 0.f}, {0.f, 0.f, 0.f, 0.f}};
#pragma unroll
        for (int oh = 0; oh < 2; oh++) {
            acc[oh] = __builtin_amdgcn_mfma_f32_16x16x32_bf16(aE0, bfr[0][oh], acc[oh], 0, 0, 0);
            acc[oh] = __builtin_amdgcn_mfma_f32_16x16x32_bf16(aS0, bfr[1][oh], acc[oh], 0, 0, 0);
            acc[oh] = __builtin_amdgcn_mfma_f32_16x16x32_bf16(aR0, bfr[2][oh], acc[oh], 0, 0, 0);
        }

        // issue loads for tile t+8 (two slots ahead; covered by ~2 tiles of work)
        bf16x8 aE2 = aE0, aS2 = aS0, aR2 = aR0, old2 = old0;
        if (t + 8 < nt) {
            int jb = beg + (t + 8) * 16;
            int ja = min(jb + n_, N_EDGES - 1);
            aE2  = *(const bf16x8*)&e[(size_t)ja * 32 + quad * 8];
            aS2  = *(const bf16x8*)&hbf_in[(size_t)(srA & 0xFFFFu) * 32 + quad * 8];
            aR2  = *(const bf16x8*)&hbf_in[(size_t)(srA >> 16) * 32 + quad * 8];
            old2 = *(const bf16x8*)&e[(size_t)min(jb + rr, N_EDGES - 1) * 32 + jj * 8];
        }
        if (t + 12 < nt)
            srA = srp[min(beg + (t + 12) * 16 + n_, N_EDGES - 1)];

        // stage leaky(acc+bias) to LDS transpose buffer
#pragma unroll
        for (int oh = 0; oh < 2; oh++)
#pragma unroll
            for (int g = 0; g < 4; g++)
                mystg[(quad * 4 + g) * STG_STRIDE + oh * 16 + n_] =
                    leaky(acc[oh][g] + (oh ? bia1 : bia0));
        __builtin_amdgcn_wave_barrier();

        // re-role: lane handles row rr, cols jj*8 .. jj*8+8
        f32x4 va = *(const f32x4*)&mystg[rr * STG_STRIDE + jj * 8];
        f32x4 vb = *(const f32x4*)&mystg[rr * STG_STRIDE + jj * 8 + 4];
        float s1 = va[0] + va[1] + va[2] + va[3] + vb[0] + vb[1] + vb[2] + vb[3];
        float s2 = va[0]*va[0] + va[1]*va[1] + va[2]*va[2] + va[3]*va[3]
                 + vb[0]*vb[0] + vb[1]*vb[1] + vb[2]*vb[2] + vb[3]*vb[3];
        s1 += __shfl_xor(s1, 1);  s2 += __shfl_xor(s2, 1);
        s1 += __shfl_xor(s1, 2);  s2 += __shfl_xor(s2, 2);
        float mu = s1 * (1.0f / 32.0f);
        float var = s2 * (1.0f / 32.0f) - mu * mu;
        float inv = rsqrtf(fmaxf(var, 0.0f) + LN_EPS);

        float v[8] = {va[0], va[1], va[2], va[3], vb[0], vb[1], vb[2], vb[3]};
        bf16x8 outp;
#pragma unroll
        for (int i = 0; i < 8; i++)
            outp[i] = (__bf16)((float)old0[i] + (v[i] - mu) * inv * lns8[i] + lnb8[i]);
        if (e0 + rr < end)
            *(bf16x8*)&e[(size_t)(e0 + rr) * 32 + jj * 8] = outp;  // coalesced 16B
        __builtin_amdgcn_wave_barrier();

        aE0 = aE1; aS0 = aS1; aR0 = aR1; old0 = old1;
        aE1 = aE2; aS1 = aS2; aR1 = aR2; old1 = old2;
    }

    __syncthreads();   // phase boundary: all e-rows of this block written

    // ---------------- phase 2: node update (8 threads / node, own-output) -
    const int nl = tid >> 3;   // node-local 0..31
    const int oc = tid & 7;    // output col quad: cols oc*4 .. oc*4+4
    const bool act = nl < nn;
    const int n = n0 + nl;
    float hv4[4] = {0.f, 0.f, 0.f, 0.f};
    float res[4] = {0.f, 0.f, 0.f, 0.f};
    if (act) {
        int bn = row_start[n], en = row_start[n + 1];
        float s4[4] = {0.f, 0.f, 0.f, 0.f};
        int j = bn;
        for (; j + 7 < en; j += 8) {
            bf16x4 v0 = *(const bf16x4*)&e[(size_t)(j + 0) * 32 + oc * 4];
            bf16x4 v1 = *(const bf16x4*)&e[(size_t)(j + 1) * 32 + oc * 4];
            bf16x4 v2 = *(const bf16x4*)&e[(size_t)(j + 2) * 32 + oc * 4];
            bf16x4 v3 = *(const bf16x4*)&e[(size_t)(j + 3) * 32 + oc * 4];
            bf16x4 v4 = *(const bf16x4*)&e[(size_t)(j + 4) * 32 + oc * 4];
            bf16x4 v5 = *(const bf16x4*)&e[(size_t)(j + 5) * 32 + oc * 4];
            bf16x4 v6 = *(const bf16x4*)&e[(size_t)(j + 6) * 32 + oc * 4];
            bf16x4 v7 = *(const bf16x4*)&e[(size_t)(j + 7) * 32 + oc * 4];
#pragma unroll
            for (int k = 0; k < 4; k++)
                s4[k] += ((float)v0[k] + (float)v1[k]) + ((float)v2[k] + (float)v3[k])
                       + ((float)v4[k] + (float)v5[k]) + ((float)v6[k] + (float)v7[k]);
        }
        for (; j < en; j++) {
            bf16x4 v = *(const bf16x4*)&e[(size_t)j * 32 + oc * 4];
#pragma unroll
            for (int k = 0; k < 4; k++) s4[k] += (float)v[k];
        }
        float ic = 1.0f / fmaxf((float)(en - bn), 1.0f);
        float4 hvv = *(const float4*)&h_in[(size_t)n * 32 + oc * 4];
        hv4[0] = hvv.x; hv4[1] = hvv.y; hv4[2] = hvv.z; hv4[3] = hvv.w;
        // stage this thread's 8 c-values into the column-layout cL
#pragma unroll
        for (int i = 0; i < 4; i++) {
            cL[(oc * 4 + i) * CL_STRIDE + nl] = hv4[i];
            cL[(32 + oc * 4 + i) * CL_STRIDE + nl] = s4[i] * ic;
        }
    }
    __syncthreads();
    if (act) {
        float4 acc = *(const float4*)&prm[oc * 4];
#pragma unroll
        for (int k = 0; k < 64; k++) {
            float ck = cL[k * CL_STRIDE + nl];                 // oc-broadcast
            acc = f4fma(ck, *(const float4*)&Ws[k * 32 + oc * 4], acc);
        }
        float m4[4] = {leaky(acc.x), leaky(acc.y), leaky(acc.z), leaky(acc.w)};
        float s1 = m4[0] + m4[1] + m4[2] + m4[3];
        float s2 = m4[0]*m4[0] + m4[1]*m4[1] + m4[2]*m4[2] + m4[3]*m4[3];
        s1 += __shfl_xor(s1, 1);  s2 += __shfl_xor(s2, 1);
        s1 += __shfl_xor(s1, 2);  s2 += __shfl_xor(s2, 2);
        s1 += __shfl_xor(s1, 4);  s2 += __shfl_xor(s2, 4);
        float mu = s1 * (1.0f / 32.0f);
        float var = s2 * (1.0f / 32.0f) - mu * mu;
        float inv = rsqrtf(fmaxf(var, 0.0f) + LN_EPS);
#pragma unroll
        for (int k = 0; k < 4; k++)
            res[k] = hv4[k] + (m4[k] - mu) * inv * prm[32 + oc * 4 + k] + prm[64 + oc * 4 + k];
        float4 r0 = {res[0], res[1], res[2], res[3]};
        *(float4*)&h_out[(size_t)n * 32 + oc * 4] = r0;
        *(bf16x4*)&hbf_out[(size_t)n * 32 + oc * 4] = pack4(r0);
    }

    // ---------------- fused decoder (last step only) ----------------------
    if (last) {
        __syncthreads();   // all cL reads of the MLP above are complete
        if (act) {
#pragma unroll
            for (int i = 0; i < 4; i++)
                cL[(oc * 4 + i) * CL_STRIDE + nl] = res[i];   // stage final h row
        }
        __syncthreads();
        if (act) {
            float4 z = *(const float4*)&db1[oc * 4];
#pragma unroll
            for (int k = 0; k < 32; k++) {
                float ck = cL[k * CL_STRIDE + nl];             // oc-broadcast
                z = f4fma(ck, *(const float4*)&dW1[k * 32 + oc * 4], z);
            }
            float4 w2 = *(const float4*)&dW2[oc * 4];
            float o = leaky(z.x) * w2.x + leaky(z.y) * w2.y
                    + leaky(z.z) * w2.z + leaky(z.w) * w2.w;
            o += __shfl_xor(o, 1);
            o += __shfl_xor(o, 2);
            o += __shfl_xor(o, 4);
            if (oc == 0) out[n] = o + db2[0];
        }
    }
}

// ---------------- launch ----------------

extern "C" void kernel_launch(void* const* d_in, const int* in_sizes, int n_in,
                              void* d_out, int out_size, void* d_ws, size_t ws_size,
                              hipStream_t stream) {
    const float* x          = (const float*)d_in[0];
    const float* edge_attr  = (const float*)d_in[1];
    const int*   senders    = (const int*)d_in[2];
    const int*   receivers  = (const int*)d_in[3];
    const float* node_enc_W = (const float*)d_in[4];
    const float* node_enc_b = (const float*)d_in[5];
    const float* edge_enc_W = (const float*)d_in[6];
    const float* edge_enc_b = (const float*)d_in[7];
    const float* edge_W     = (const float*)d_in[8];
    const float* edge_b     = (const float*)d_in[9];
    const float* edge_ln_s  = (const float*)d_in[10];
    const float* edge_ln_b  = (const float*)d_in[11];
    const float* node_W     = (const float*)d_in[12];
    const float* node_b     = (const float*)d_in[13];
    const float* node_ln_s  = (const float*)d_in[14];
    const float* node_ln_b  = (const float*)d_in[15];
    const float* dec_W1     = (const float*)d_in[16];
    const float* dec_b1     = (const float*)d_in[17];
    const float* dec_W2     = (const float*)d_in[18];
    const float* dec_b2     = (const float*)d_in[19];
    float* out = (float*)d_out;

    char* ws = (char*)d_ws;
    size_t off = 0;
    auto alloc = [&](size_t bytes) -> void* {
        void* p = ws + off;
        off = (off + bytes + 255) & ~(size_t)255;
        return p;
    };
    float*        h0        = (float*)alloc((size_t)N_NODES * 32 * 4);
    float*        h1        = (float*)alloc((size_t)N_NODES * 32 * 4);
    __bf16*       hbf0      = (__bf16*)alloc((size_t)N_NODES * 32 * 2);
    __bf16*       hbf1      = (__bf16*)alloc((size_t)N_NODES * 32 * 2);
    __bf16*       e         = (__bf16*)alloc((size_t)N_EDGES * 32 * 2);
    int*          cnt       = (int*)alloc((size_t)N_NODES * 4);
    int*          row_start = (int*)alloc((size_t)(N_NODES + 1) * 4);
    int*          cursor    = (int*)alloc((size_t)N_NODES * 4);
    unsigned int* sr_p      = (unsigned int*)alloc((size_t)N_EDGES * 4);
    int*          partial   = (int*)alloc((size_t)SCAN_BLK * 4);
    (void)ws_size; (void)in_sizes; (void)n_in; (void)out_size;

    hipMemsetAsync(cnt, 0, (size_t)N_NODES * 4, stream);
    encode_nodes_kernel<<<(N_NODES + 255) / 256, 256, 0, stream>>>(x, node_enc_W, node_enc_b, h0, hbf0);
    count_kernel<<<(N_EDGES + 255) / 256, 256, 0, stream>>>(receivers, cnt);
    csr_reduce_kernel<<<SCAN_NBLK, SCAN_BLK, 0, stream>>>(cnt, partial);
    csr_scan_partials_kernel<<<1, SCAN_BLK, 0, stream>>>(partial, row_start);
    csr_apply_kernel<<<SCAN_NBLK, SCAN_BLK, 0, stream>>>(cnt, partial, row_start, cursor);
    scatter_encode_kernel<<<(N_EDGES + 255) / 256, 256, 0, stream>>>(
        edge_attr, senders, receivers, cursor, edge_enc_W, edge_enc_b, e, sr_p);

    float*  hbufs[2]  = {h0, h1};
    __bf16* hbbufs[2] = {hbf0, hbf1};
    for (int s = 0; s < STEPS; s++) {
        int in = s & 1, outb = 1 - in;
        fused_step_kernel<<<STEP_BLOCKS, 256, 0, stream>>>(
            e, hbbufs[in], hbbufs[outb], hbufs[in], hbufs[outb],
            sr_p, row_start,
            edge_W + (size_t)s * 96 * 32, edge_b + s * 32,
            edge_ln_s + s * 32, edge_ln_b + s * 32,
            node_W + (size_t)s * 64 * 32, node_b + s * 32,
            node_ln_s + s * 32, node_ln_b + s * 32,
            dec_W1, dec_b1, dec_W2, dec_b2, out,
            (s == STEPS - 1) ? 1 : 0);
    }
}